// Round 27
// baseline (300.408 us; speedup 1.0000x reference)
//
#include <hip/hip_runtime.h>
#include <hip/hip_fp16.h>
#include <math.h>

#define NN 50000
#define EE 800000
#define INDIM 10
#define EMB 32
#define HID 128
#define NLAYERS 3
#define BN_EPS 1e-5f
#define CAP 64                                // padded CSR slots per node (4B each)

#define FPART 8                               // one partition per XCD
#define FCHUNK 2048                           // edges per chunk

typedef _Float16 h2v __attribute__((ext_vector_type(2)));
__device__ __forceinline__ float fdot2(__half2 a, __half2 b, float c) {
    return __builtin_amdgcn_fdot2(*(h2v*)&a, *(h2v*)&b, c, false);
}

__device__ __forceinline__ int clampN(int v) {
    return v < 0 ? 0 : (v >= NN ? NN - 1 : v);
}

__device__ __forceinline__ void accum8(float acc[8], float4 v, float w) {
    const __half2* hh = (const __half2*)&v;
    #pragma unroll
    for (int k = 0; k < 4; ++k) {
        float2 f = __half22float2(hh[k]);
        acc[2 * k]     = fmaf(f.x, w, acc[2 * k]);
        acc[2 * k + 1] = fmaf(f.y, w, acc[2 * k + 1]);
    }
}

// --- combined init: zero cnt+deg, pack conv weights, pack comb weights ------

#define NWT (NLAYERS * 64 * HID)              // 24576
#define NWC (32 * HID)                        // 4096

__global__ void k_prep(const float* __restrict__ convW,
                       const float* __restrict__ combW,
                       __half2* __restrict__ Wtp, __half2* __restrict__ Wctp,
                       int* __restrict__ cursor, float* __restrict__ deg) {
    int idx = blockIdx.x * blockDim.x + threadIdx.x;
    if (idx < NN) { cursor[idx] = 0; deg[idx] = 0.f; }
    if (idx < NWT) {
        int L = idx / (64 * HID);
        int rem = idx - L * 64 * HID;
        int kk = rem >> 7, c = rem & 127;
        const float* Wl = convW + L * HID * HID + c * HID;
        Wtp[idx] = __floats2half2_rn(Wl[2 * kk], Wl[2 * kk + 1]);
    } else if (idx - NWT < NWC) {
        int j = idx - NWT;
        int kk = j >> 7, c = j & 127;
        const float* Wc = combW + c * (2 * EMB);
        Wctp[j] = __floats2half2_rn(Wc[2 * kk], Wc[2 * kk + 1]);
    }
}

// XCD-partitioned build: scatter packed CSR entry AND accumulate fp32 degree.
// Both cursor/deg/csr slices for a partition stay in one XCD's L2.
__global__ __launch_bounds__(256) void k_fill(const int* __restrict__ ei,
                                              const float* __restrict__ ew,
                                              int* __restrict__ cursor,
                                              float* __restrict__ deg,
                                              unsigned* __restrict__ csr) {
    int part = blockIdx.x & (FPART - 1);
    int base = (blockIdx.x >> 3) * FCHUNK;
    int end = base + FCHUNK; if (end > EE) end = EE;
    for (int e = base + threadIdx.x; e < end; e += 256) {
        int c = clampN(ei[EE + e]);
        if ((c * FPART) / NN != part) continue;   // not my partition
        int r = clampN(ei[e]);
        float w = ew[e];
        int pos = atomicAdd(&cursor[c], 1);
        if (pos >= CAP) pos = CAP - 1;            // defensive (P ~ 1e-11)
        unsigned short hw = __half_as_ushort(__float2half(w));
        unsigned v = (unsigned)(unsigned short)r | ((unsigned)hw << 16);
        csr[(size_t)c * CAP + pos] = v;           // regular store: let L2 merge
        atomicAdd(&deg[c], w);                    // fp32 deg, XCD-local line
    }
}

// ---- prologue via fdot2: h = relu([emb, x@ftW.T+ftb] @ combW.T + combb) ----
// also finalizes dinv[n] = rsqrt(1 + deg[n])  (fill completed upstream)

__global__ __launch_bounds__(256) void k_init_h(
        const float* __restrict__ x, const float* __restrict__ emb,
        const float* __restrict__ ftW, const float* __restrict__ ftb,
        const __half2* __restrict__ Wctp, const float* __restrict__ combb,
        const float* __restrict__ deg, float* __restrict__ dinv,
        float* __restrict__ h) {
    __shared__ __half2 csh2[64 * 34];             // 8.7 KB; 32 data + 2 pad
    __shared__ float xsh[64 * INDIM];             // 2.5 KB
    int t = threadIdx.x;
    int n0 = blockIdx.x * 64;

    if (t < 64) {                                 // dinv for this block's nodes
        int n = n0 + t;
        if (n < NN) dinv[n] = rsqrtf(1.0f + deg[n]);
    }
    for (int s = t; s < 64 * INDIM; s += 256) {
        int j = s / INDIM, q = s - j * INDIM;
        float xv = (n0 + j < NN) ? x[(n0 + j) * INDIM + q] : 0.f;
        unsigned bits = __float_as_uint(xv) & 0x7fffffffu;
        if (bits > 0x7f800000u) xv = 0.f;
        xsh[s] = xv;
    }
    __syncthreads();
    #pragma unroll
    for (int i = 0; i < 8; ++i) {
        int s = i * 256 + t;                      // 0..2047
        int j = s >> 5, kk = s & 31;
        int n = n0 + j;
        __half2 v;
        if (kk < 16) {                            // emb pair (2kk, 2kk+1)
            float2 e2 = (n < NN) ? *(const float2*)&emb[(size_t)n * EMB + 2 * kk]
                                 : make_float2(0.f, 0.f);
            v = __floats2half2_rn(e2.x, e2.y);
        } else {                                  // feat pair
            int f0 = 2 * (kk - 16);
            float a0 = ftb[f0], a1 = ftb[f0 + 1];
            #pragma unroll
            for (int q = 0; q < INDIM; ++q) {
                float xv = xsh[j * INDIM + q];
                a0 = fmaf(ftW[f0 * INDIM + q], xv, a0);
                a1 = fmaf(ftW[(f0 + 1) * INDIM + q], xv, a1);
            }
            v = __floats2half2_rn(a0, a1);
        }
        csh2[j * 34 + kk] = v;
    }
    __syncthreads();

    int ty = t >> 4, tx = t & 15;
    float acc[4][8];
    #pragma unroll
    for (int i = 0; i < 4; ++i)
        #pragma unroll
        for (int j = 0; j < 8; ++j) acc[i][j] = 0.f;

    #pragma unroll 2
    for (int k2 = 0; k2 < 32; ++k2) {
        const __half2* wr = &Wctp[k2 * HID + tx * 8];
        __half2 wf[8];
        *(float4*)&wf[0] = *(const float4*)&wr[0];
        *(float4*)&wf[4] = *(const float4*)&wr[4];
        __half2 hf[4];
        #pragma unroll
        for (int i = 0; i < 4; ++i) hf[i] = csh2[(ty * 4 + i) * 34 + k2];
        #pragma unroll
        for (int i = 0; i < 4; ++i)
            #pragma unroll
            for (int j = 0; j < 8; ++j)
                acc[i][j] = fdot2(hf[i], wf[j], acc[i][j]);
    }
    #pragma unroll
    for (int i = 0; i < 4; ++i) {
        int n = n0 + ty * 4 + i;
        if (n < NN) {
            #pragma unroll
            for (int j = 0; j < 8; ++j)
                acc[i][j] = fmaxf(acc[i][j] + combb[tx * 8 + j], 0.f);
            *(float4*)&h[(size_t)n * HID + tx * 8]     = *(float4*)&acc[i][0];
            *(float4*)&h[(size_t)n * HID + tx * 8 + 4] = *(float4*)&acc[i][4];
        }
    }
}

// --- per-layer GEMM via v_dot2_f32_f16, W staged in LDS --------------------

#define BM 64
__global__ __launch_bounds__(256) void k_gemm(const float* __restrict__ h,
                                              const __half2* __restrict__ Wtp,
                                              const float* __restrict__ dinv,
                                              __half* __restrict__ xt) {
    __shared__ __half2 hsh[BM * 66];              // 16.9 KB; 64 data + 2 pad
    __shared__ __half2 wsh[64 * HID];             // 32 KB, [k2][c]
    int t = threadIdx.x;
    int row0 = blockIdx.x * BM;
    // stage W layer (contiguous copy)
    #pragma unroll
    for (int i = 0; i < 8; ++i) {
        int s = i * 256 + t;                      // float4 idx 0..2047
        ((float4*)wsh)[s] = ((const float4*)Wtp)[s];
    }
    // stage h tile as half2
    #pragma unroll
    for (int i = 0; i < 8; ++i) {
        int s = i * 256 + t;                      // float4 index 0..2047
        int r = s >> 5;
        int cc = s & 31;
        float4 v = make_float4(0.f, 0.f, 0.f, 0.f);
        int row = row0 + r;
        if (row < NN) v = *(const float4*)&h[row * HID + cc * 4];
        hsh[r * 66 + cc * 2]     = __floats2half2_rn(v.x, v.y);
        hsh[r * 66 + cc * 2 + 1] = __floats2half2_rn(v.z, v.w);
    }
    __syncthreads();
    int ty = t >> 4, tx = t & 15;
    float acc[4][8];
    #pragma unroll
    for (int i = 0; i < 4; ++i)
        #pragma unroll
        for (int j = 0; j < 8; ++j) acc[i][j] = 0.f;

    #pragma unroll 4
    for (int k2 = 0; k2 < 64; ++k2) {             // half2 index along K
        const __half2* wr = &wsh[k2 * HID + tx * 8];
        __half2 wf[8];
        *(float4*)&wf[0] = *(const float4*)&wr[0];
        *(float4*)&wf[4] = *(const float4*)&wr[4];
        __half2 hf[4];
        #pragma unroll
        for (int i = 0; i < 4; ++i) hf[i] = hsh[(ty * 4 + i) * 66 + k2];
        #pragma unroll
        for (int i = 0; i < 4; ++i)
            #pragma unroll
            for (int j = 0; j < 8; ++j)
                acc[i][j] = fdot2(hf[i], wf[j], acc[i][j]);
    }
    #pragma unroll
    for (int i = 0; i < 4; ++i) {
        int row = row0 + ty * 4 + i;
        if (row < NN) {
            float dv = dinv[row];                 // fold D^{-1/2} (src side)
            __half2 p0 = __floats2half2_rn(acc[i][0] * dv, acc[i][1] * dv);
            __half2 p1 = __floats2half2_rn(acc[i][2] * dv, acc[i][3] * dv);
            __half2 p2 = __floats2half2_rn(acc[i][4] * dv, acc[i][5] * dv);
            __half2 p3 = __floats2half2_rn(acc[i][6] * dv, acc[i][7] * dv);
            uint4 u = make_uint4(*(unsigned*)&p0, *(unsigned*)&p1,
                                 *(unsigned*)&p2, *(unsigned*)&p3);
            *(uint4*)&xt[(size_t)row * HID + tx * 8] = u;
        }
    }
}

// ------- aggregation + self-loop + bias + relu + BN + residual (in-place h) -
// 16-lane group per node; lane q holds features [8q, 8q+8). 8-deep pipeline.

__global__ __launch_bounds__(256) void k_aggregate(
        const __half* __restrict__ xt, float* __restrict__ h,
        const int* __restrict__ cnt, const unsigned* __restrict__ csr,
        const float* __restrict__ dinv,
        const float* __restrict__ bias, const float* __restrict__ gamma,
        const float* __restrict__ beta, const float* __restrict__ mean,
        const float* __restrict__ var,
        const float* __restrict__ linW, const float* __restrict__ linb,
        float* __restrict__ out, int last) {
    int g = threadIdx.x >> 4, q = threadIdx.x & 15;
    int n = blockIdx.x * 16 + g;
    if (n >= NN) return;
    const float4* xt4 = (const float4*)xt;        // row = 16 float4 (128 fp16)
    const unsigned* seg = &csr[(size_t)n * CAP];
    int m = cnt[n]; if (m > CAP) m = CAP;
    float acc[8];
    #pragma unroll
    for (int j = 0; j < 8; ++j) acc[j] = 0.f;
    int i = 0;
    for (; i + 7 < m; i += 8) {                   // 8 row-gathers in flight
        unsigned p_[8];
        #pragma unroll
        for (int u = 0; u < 8; ++u) p_[u] = seg[i + u];
        float4 r_[8];
        #pragma unroll
        for (int u = 0; u < 8; ++u)
            r_[u] = xt4[(size_t)(p_[u] & 0xffffu) * 16 + q];
        #pragma unroll
        for (int u = 0; u < 8; ++u) {
            float w = __half2float(__ushort_as_half((unsigned short)(p_[u] >> 16)));
            accum8(acc, r_[u], w);
        }
    }
    for (; i < m; ++i) {
        unsigned p = seg[i];
        float4 r = xt4[(size_t)(p & 0xffffu) * 16 + q];
        float w = __half2float(__ushort_as_half((unsigned short)(p >> 16)));
        accum8(acc, r, w);
    }
    accum8(acc, xt4[(size_t)n * 16 + q], 1.0f);   // self: + xt'[n]
    float dn = dinv[n];

    int c0 = q * 8;
    float hres[8];
    *(float4*)&hres[0] = *(const float4*)&h[(size_t)n * HID + c0];
    *(float4*)&hres[4] = *(const float4*)&h[(size_t)n * HID + c0 + 4];
    float outv[8];
    #pragma unroll
    for (int j = 0; j < 8; ++j) {
        float v = fmaxf(acc[j] * dn + bias[c0 + j], 0.f);
        v = (v - mean[c0 + j]) * rsqrtf(var[c0 + j] + BN_EPS) * gamma[c0 + j]
            + beta[c0 + j];
        outv[j] = v + hres[j];
    }
    if (!last) {
        *(float4*)&h[(size_t)n * HID + c0]     = *(float4*)&outv[0];
        *(float4*)&h[(size_t)n * HID + c0 + 4] = *(float4*)&outv[4];
    } else {
        // fused final: out[n] = clip(sum_c h_new[c]*linW[c] + linb, -10, 10)
        float s = 0.f;
        #pragma unroll
        for (int j = 0; j < 8; ++j) s = fmaf(outv[j], linW[c0 + j], s);
        #pragma unroll
        for (int o = 8; o; o >>= 1) s += __shfl_xor(s, o, 64);  // 16-lane red.
        if (q == 0) {
            float o = s + linb[0];
            out[n] = fminf(fmaxf(o, -10.f), 10.f);
        }
    }
}

// ---------------- launch ----------------------------------------------------

extern "C" void kernel_launch(void* const* d_in, const int* in_sizes, int n_in,
                              void* d_out, int out_size, void* d_ws, size_t ws_size,
                              hipStream_t stream) {
    const float* x     = (const float*)d_in[0];
    const int*   ei    = (const int*)d_in[1];     // int32: harness narrows int64
    const float* ew    = (const float*)d_in[2];
    const float* emb   = (const float*)d_in[3];
    const float* ftW   = (const float*)d_in[4];
    const float* ftb   = (const float*)d_in[5];
    const float* combW = (const float*)d_in[6];
    const float* combb = (const float*)d_in[7];
    const float* convW = (const float*)d_in[8];
    const float* convb = (const float*)d_in[9];
    const float* gamma = (const float*)d_in[10];
    const float* beta  = (const float*)d_in[11];
    const float* mean  = (const float*)d_in[12];
    const float* var   = (const float*)d_in[13];
    const float* linW  = (const float*)d_in[14];
    const float* linb  = (const float*)d_in[15];
    float* out = (float*)d_out;

    char* ws = (char*)d_ws;
    size_t off = 0;
    auto alloc = [&](size_t bytes) {
        void* p = ws + off;
        off = (off + bytes + 255) & ~(size_t)255;
        return p;
    };
    float*    h    = (float*)alloc((size_t)NN * HID * 4);
    __half*   xt   = (__half*)alloc((size_t)NN * HID * 2);
    float*    dinv = (float*)alloc((size_t)NN * 4);
    float*    deg  = (float*)alloc((size_t)NN * 4);
    int*      cnt  = (int*)alloc((size_t)NN * 4);        // cursor -> counts
    unsigned* csr  = (unsigned*)alloc((size_t)NN * CAP * 4); // packed CSR, 12.8 MB
    __half2*  Wtp  = (__half2*)alloc((size_t)NWT * 4);
    __half2*  Wctp = (__half2*)alloc((size_t)NWC * 4);

    const int NBK = (NN + 255) / 256;        // 196 (covers NWT+NWC too)
    const int FB = ((EE + FCHUNK - 1) / FCHUNK) * FPART; // 391*8 = 3128
    const int AGB = (NN + 15) / 16;          // 3125
    const int IHB = (NN + 63) / 64;          // 782

    k_prep<<<NBK, 256, 0, stream>>>(convW, combW, Wtp, Wctp, cnt, deg);
    k_fill<<<FB, 256, 0, stream>>>(ei, ew, cnt, deg, csr);
    k_init_h<<<IHB, 256, 0, stream>>>(x, emb, ftW, ftb, Wctp, combb, deg, dinv, h);
    for (int L = 0; L < NLAYERS; ++L) {
        k_gemm<<<(NN + BM - 1) / BM, 256, 0, stream>>>(h, Wtp + (size_t)L * 64 * HID, dinv, xt);
        k_aggregate<<<AGB, 256, 0, stream>>>(xt, h, cnt, csr, dinv,
                                             convb + L * HID, gamma, beta, mean, var,
                                             linW, linb, out, L == NLAYERS - 1);
    }
}

// Round 28
// 271.814 us; speedup vs baseline: 1.1052x; 1.1052x over previous
//
#include <hip/hip_runtime.h>
#include <hip/hip_fp16.h>
#include <math.h>

#define NN 50000
#define EE 800000
#define INDIM 10
#define EMB 32
#define HID 128
#define NLAYERS 3
#define BN_EPS 1e-5f
#define CAP 64                                // padded CSR slots per node (4B each)

#define FPART 8                               // one partition per XCD
#define FCHUNK 2048                           // edges per chunk

typedef _Float16 h2v __attribute__((ext_vector_type(2)));
__device__ __forceinline__ float fdot2(__half2 a, __half2 b, float c) {
    return __builtin_amdgcn_fdot2(*(h2v*)&a, *(h2v*)&b, c, false);
}

__device__ __forceinline__ int clampN(int v) {
    return v < 0 ? 0 : (v >= NN ? NN - 1 : v);
}

__device__ __forceinline__ void accum8(float acc[8], float4 v, float w) {
    const __half2* hh = (const __half2*)&v;
    #pragma unroll
    for (int k = 0; k < 4; ++k) {
        float2 f = __half22float2(hh[k]);
        acc[2 * k]     = fmaf(f.x, w, acc[2 * k]);
        acc[2 * k + 1] = fmaf(f.y, w, acc[2 * k + 1]);
    }
}

// -------- combined init: zero cnt + pack conv weights + pack comb weights ---

#define NWT (NLAYERS * 64 * HID)              // 24576
#define NWC (32 * HID)                        // 4096

__global__ void k_prep(const float* __restrict__ convW,
                       const float* __restrict__ combW,
                       __half2* __restrict__ Wtp, __half2* __restrict__ Wctp,
                       int* __restrict__ cursor) {
    int idx = blockIdx.x * blockDim.x + threadIdx.x;
    if (idx < NN) cursor[idx] = 0;
    if (idx < NWT) {
        int L = idx / (64 * HID);
        int rem = idx - L * 64 * HID;
        int kk = rem >> 7, c = rem & 127;
        const float* Wl = convW + L * HID * HID + c * HID;
        Wtp[idx] = __floats2half2_rn(Wl[2 * kk], Wl[2 * kk + 1]);
    } else if (idx - NWT < NWC) {
        int j = idx - NWT;
        int kk = j >> 7, c = j & 127;
        const float* Wc = combW + c * (2 * EMB);
        Wctp[j] = __floats2half2_rn(Wc[2 * kk], Wc[2 * kk + 1]);
    }
}

// XCD-partitioned build: block (chunk, part) scatters only edges whose target
// lies in partition part. Round-robin block->XCD keeps each node's CSR line
// owned by one XCD's L2 so partial-line stores merge before writeback.
__global__ __launch_bounds__(256) void k_fill(const int* __restrict__ ei,
                                              const float* __restrict__ ew,
                                              int* __restrict__ cursor,
                                              unsigned* __restrict__ csr) {
    int part = blockIdx.x & (FPART - 1);
    int base = (blockIdx.x >> 3) * FCHUNK;
    int end = base + FCHUNK; if (end > EE) end = EE;
    for (int e = base + threadIdx.x; e < end; e += 256) {
        int c = clampN(ei[EE + e]);
        if ((c * FPART) / NN != part) continue;   // not my partition
        int r = clampN(ei[e]);
        int pos = atomicAdd(&cursor[c], 1);
        if (pos >= CAP) pos = CAP - 1;            // defensive (P ~ 1e-11)
        unsigned short hw = __half_as_ushort(__float2half(ew[e]));
        unsigned v = (unsigned)(unsigned short)r | ((unsigned)hw << 16);
        csr[(size_t)c * CAP + pos] = v;           // regular store: let L2 merge
    }
}

// wave per node: deg = 1 + sum(segment fp16 ew) -> dinv = rsqrt(deg)
__global__ __launch_bounds__(256) void k_deg(const unsigned* __restrict__ csr,
                                             const int* __restrict__ cnt,
                                             float* __restrict__ dinv) {
    int n = blockIdx.x * 4 + (threadIdx.x >> 6);
    int l = threadIdx.x & 63;
    if (n >= NN) return;
    int m = cnt[n]; if (m > CAP) m = CAP;
    const unsigned* seg = &csr[(size_t)n * CAP];
    float s = 0.f;
    for (int i = l; i < m; i += 64)
        s += __half2float(__ushort_as_half((unsigned short)(seg[i] >> 16)));
    #pragma unroll
    for (int o = 32; o; o >>= 1) s += __shfl_xor(s, o, 64);
    if (l == 0) dinv[n] = rsqrtf(1.0f + s);       // deg >= 1 always
}

// ---- prologue via fdot2: h = relu([emb, x@ftW.T+ftb] @ combW.T + combb) ----

__global__ __launch_bounds__(256) void k_init_h(
        const float* __restrict__ x, const float* __restrict__ emb,
        const float* __restrict__ ftW, const float* __restrict__ ftb,
        const __half2* __restrict__ Wctp, const float* __restrict__ combb,
        float* __restrict__ h) {
    __shared__ __half2 csh2[64 * 34];             // 8.7 KB; 32 data + 2 pad
    __shared__ float xsh[64 * INDIM];             // 2.5 KB
    int t = threadIdx.x;
    int n0 = blockIdx.x * 64;

    for (int s = t; s < 64 * INDIM; s += 256) {
        int j = s / INDIM, q = s - j * INDIM;
        float xv = (n0 + j < NN) ? x[(n0 + j) * INDIM + q] : 0.f;
        unsigned bits = __float_as_uint(xv) & 0x7fffffffu;
        if (bits > 0x7f800000u) xv = 0.f;
        xsh[s] = xv;
    }
    __syncthreads();
    #pragma unroll
    for (int i = 0; i < 8; ++i) {
        int s = i * 256 + t;                      // 0..2047
        int j = s >> 5, kk = s & 31;
        int n = n0 + j;
        __half2 v;
        if (kk < 16) {                            // emb pair (2kk, 2kk+1)
            float2 e2 = (n < NN) ? *(const float2*)&emb[(size_t)n * EMB + 2 * kk]
                                 : make_float2(0.f, 0.f);
            v = __floats2half2_rn(e2.x, e2.y);
        } else {                                  // feat pair
            int f0 = 2 * (kk - 16);
            float a0 = ftb[f0], a1 = ftb[f0 + 1];
            #pragma unroll
            for (int q = 0; q < INDIM; ++q) {
                float xv = xsh[j * INDIM + q];
                a0 = fmaf(ftW[f0 * INDIM + q], xv, a0);
                a1 = fmaf(ftW[(f0 + 1) * INDIM + q], xv, a1);
            }
            v = __floats2half2_rn(a0, a1);
        }
        csh2[j * 34 + kk] = v;
    }
    __syncthreads();

    int ty = t >> 4, tx = t & 15;
    float acc[4][8];
    #pragma unroll
    for (int i = 0; i < 4; ++i)
        #pragma unroll
        for (int j = 0; j < 8; ++j) acc[i][j] = 0.f;

    #pragma unroll 2
    for (int k2 = 0; k2 < 32; ++k2) {
        const __half2* wr = &Wctp[k2 * HID + tx * 8];
        __half2 wf[8];
        *(float4*)&wf[0] = *(const float4*)&wr[0];
        *(float4*)&wf[4] = *(const float4*)&wr[4];
        __half2 hf[4];
        #pragma unroll
        for (int i = 0; i < 4; ++i) hf[i] = csh2[(ty * 4 + i) * 34 + k2];
        #pragma unroll
        for (int i = 0; i < 4; ++i)
            #pragma unroll
            for (int j = 0; j < 8; ++j)
                acc[i][j] = fdot2(hf[i], wf[j], acc[i][j]);
    }
    #pragma unroll
    for (int i = 0; i < 4; ++i) {
        int n = n0 + ty * 4 + i;
        if (n < NN) {
            #pragma unroll
            for (int j = 0; j < 8; ++j)
                acc[i][j] = fmaxf(acc[i][j] + combb[tx * 8 + j], 0.f);
            *(float4*)&h[(size_t)n * HID + tx * 8]     = *(float4*)&acc[i][0];
            *(float4*)&h[(size_t)n * HID + tx * 8 + 4] = *(float4*)&acc[i][4];
        }
    }
}

// --- per-layer GEMM via v_dot2_f32_f16, W staged in LDS --------------------

#define BM 64
__global__ __launch_bounds__(256) void k_gemm(const float* __restrict__ h,
                                              const __half2* __restrict__ Wtp,
                                              const float* __restrict__ dinv,
                                              __half* __restrict__ xt) {
    __shared__ __half2 hsh[BM * 66];              // 16.9 KB; 64 data + 2 pad
    __shared__ __half2 wsh[64 * HID];             // 32 KB, [k2][c]
    int t = threadIdx.x;
    int row0 = blockIdx.x * BM;
    // stage W layer (contiguous copy)
    #pragma unroll
    for (int i = 0; i < 8; ++i) {
        int s = i * 256 + t;                      // float4 idx 0..2047
        ((float4*)wsh)[s] = ((const float4*)Wtp)[s];
    }
    // stage h tile as half2
    #pragma unroll
    for (int i = 0; i < 8; ++i) {
        int s = i * 256 + t;                      // float4 index 0..2047
        int r = s >> 5;
        int cc = s & 31;
        float4 v = make_float4(0.f, 0.f, 0.f, 0.f);
        int row = row0 + r;
        if (row < NN) v = *(const float4*)&h[row * HID + cc * 4];
        hsh[r * 66 + cc * 2]     = __floats2half2_rn(v.x, v.y);
        hsh[r * 66 + cc * 2 + 1] = __floats2half2_rn(v.z, v.w);
    }
    __syncthreads();
    int ty = t >> 4, tx = t & 15;
    float acc[4][8];
    #pragma unroll
    for (int i = 0; i < 4; ++i)
        #pragma unroll
        for (int j = 0; j < 8; ++j) acc[i][j] = 0.f;

    #pragma unroll 4
    for (int k2 = 0; k2 < 64; ++k2) {             // half2 index along K
        const __half2* wr = &wsh[k2 * HID + tx * 8];
        __half2 wf[8];
        *(float4*)&wf[0] = *(const float4*)&wr[0];
        *(float4*)&wf[4] = *(const float4*)&wr[4];
        __half2 hf[4];
        #pragma unroll
        for (int i = 0; i < 4; ++i) hf[i] = hsh[(ty * 4 + i) * 66 + k2];
        #pragma unroll
        for (int i = 0; i < 4; ++i)
            #pragma unroll
            for (int j = 0; j < 8; ++j)
                acc[i][j] = fdot2(hf[i], wf[j], acc[i][j]);
    }
    #pragma unroll
    for (int i = 0; i < 4; ++i) {
        int row = row0 + ty * 4 + i;
        if (row < NN) {
            float dv = dinv[row];                 // fold D^{-1/2} (src side)
            __half2 p0 = __floats2half2_rn(acc[i][0] * dv, acc[i][1] * dv);
            __half2 p1 = __floats2half2_rn(acc[i][2] * dv, acc[i][3] * dv);
            __half2 p2 = __floats2half2_rn(acc[i][4] * dv, acc[i][5] * dv);
            __half2 p3 = __floats2half2_rn(acc[i][6] * dv, acc[i][7] * dv);
            uint4 u = make_uint4(*(unsigned*)&p0, *(unsigned*)&p1,
                                 *(unsigned*)&p2, *(unsigned*)&p3);
            *(uint4*)&xt[(size_t)row * HID + tx * 8] = u;
        }
    }
}

// ------- aggregation + self-loop + bias + relu + BN + residual (in-place h) -
// 16-lane group per node; lane q holds features [8q, 8q+8). 8-deep pipeline.

__global__ __launch_bounds__(256) void k_aggregate(
        const __half* __restrict__ xt, float* __restrict__ h,
        const int* __restrict__ cnt, const unsigned* __restrict__ csr,
        const float* __restrict__ dinv,
        const float* __restrict__ bias, const float* __restrict__ gamma,
        const float* __restrict__ beta, const float* __restrict__ mean,
        const float* __restrict__ var,
        const float* __restrict__ linW, const float* __restrict__ linb,
        float* __restrict__ out, int last) {
    int g = threadIdx.x >> 4, q = threadIdx.x & 15;
    int n = blockIdx.x * 16 + g;
    if (n >= NN) return;
    const float4* xt4 = (const float4*)xt;        // row = 16 float4 (128 fp16)
    const unsigned* seg = &csr[(size_t)n * CAP];
    int m = cnt[n]; if (m > CAP) m = CAP;
    float acc[8];
    #pragma unroll
    for (int j = 0; j < 8; ++j) acc[j] = 0.f;
    int i = 0;
    for (; i + 7 < m; i += 8) {                   // 8 row-gathers in flight
        unsigned p_[8];
        #pragma unroll
        for (int u = 0; u < 8; ++u) p_[u] = seg[i + u];
        float4 r_[8];
        #pragma unroll
        for (int u = 0; u < 8; ++u)
            r_[u] = xt4[(size_t)(p_[u] & 0xffffu) * 16 + q];
        #pragma unroll
        for (int u = 0; u < 8; ++u) {
            float w = __half2float(__ushort_as_half((unsigned short)(p_[u] >> 16)));
            accum8(acc, r_[u], w);
        }
    }
    for (; i < m; ++i) {
        unsigned p = seg[i];
        float4 r = xt4[(size_t)(p & 0xffffu) * 16 + q];
        float w = __half2float(__ushort_as_half((unsigned short)(p >> 16)));
        accum8(acc, r, w);
    }
    accum8(acc, xt4[(size_t)n * 16 + q], 1.0f);   // self: + xt'[n]
    float dn = dinv[n];

    int c0 = q * 8;
    float hres[8];
    *(float4*)&hres[0] = *(const float4*)&h[(size_t)n * HID + c0];
    *(float4*)&hres[4] = *(const float4*)&h[(size_t)n * HID + c0 + 4];
    float outv[8];
    #pragma unroll
    for (int j = 0; j < 8; ++j) {
        float v = fmaxf(acc[j] * dn + bias[c0 + j], 0.f);
        v = (v - mean[c0 + j]) * rsqrtf(var[c0 + j] + BN_EPS) * gamma[c0 + j]
            + beta[c0 + j];
        outv[j] = v + hres[j];
    }
    if (!last) {
        *(float4*)&h[(size_t)n * HID + c0]     = *(float4*)&outv[0];
        *(float4*)&h[(size_t)n * HID + c0 + 4] = *(float4*)&outv[4];
    } else {
        // fused final: out[n] = clip(sum_c h_new[c]*linW[c] + linb, -10, 10)
        float s = 0.f;
        #pragma unroll
        for (int j = 0; j < 8; ++j) s = fmaf(outv[j], linW[c0 + j], s);
        #pragma unroll
        for (int o = 8; o; o >>= 1) s += __shfl_xor(s, o, 64);  // 16-lane red.
        if (q == 0) {
            float o = s + linb[0];
            out[n] = fminf(fmaxf(o, -10.f), 10.f);
        }
    }
}

// ---------------- launch ----------------------------------------------------

extern "C" void kernel_launch(void* const* d_in, const int* in_sizes, int n_in,
                              void* d_out, int out_size, void* d_ws, size_t ws_size,
                              hipStream_t stream) {
    const float* x     = (const float*)d_in[0];
    const int*   ei    = (const int*)d_in[1];     // int32: harness narrows int64
    const float* ew    = (const float*)d_in[2];
    const float* emb   = (const float*)d_in[3];
    const float* ftW   = (const float*)d_in[4];
    const float* ftb   = (const float*)d_in[5];
    const float* combW = (const float*)d_in[6];
    const float* combb = (const float*)d_in[7];
    const float* convW = (const float*)d_in[8];
    const float* convb = (const float*)d_in[9];
    const float* gamma = (const float*)d_in[10];
    const float* beta  = (const float*)d_in[11];
    const float* mean  = (const float*)d_in[12];
    const float* var   = (const float*)d_in[13];
    const float* linW  = (const float*)d_in[14];
    const float* linb  = (const float*)d_in[15];
    float* out = (float*)d_out;

    char* ws = (char*)d_ws;
    size_t off = 0;
    auto alloc = [&](size_t bytes) {
        void* p = ws + off;
        off = (off + bytes + 255) & ~(size_t)255;
        return p;
    };
    float*    h    = (float*)alloc((size_t)NN * HID * 4);
    __half*   xt   = (__half*)alloc((size_t)NN * HID * 2);
    float*    dinv = (float*)alloc((size_t)NN * 4);
    int*      cnt  = (int*)alloc((size_t)NN * 4);        // cursor -> counts
    unsigned* csr  = (unsigned*)alloc((size_t)NN * CAP * 4); // packed CSR, 12.8 MB
    __half2*  Wtp  = (__half2*)alloc((size_t)NWT * 4);
    __half2*  Wctp = (__half2*)alloc((size_t)NWC * 4);

    const int NBK = (NN + 255) / 256;        // 196 (covers NWT+NWC too)
    const int FB = ((EE + FCHUNK - 1) / FCHUNK) * FPART; // 391*8 = 3128
    const int NODE4 = (NN + 3) / 4;          // 12500
    const int AGB = (NN + 15) / 16;          // 3125
    const int IHB = (NN + 63) / 64;          // 782

    k_prep<<<NBK, 256, 0, stream>>>(convW, combW, Wtp, Wctp, cnt);
    k_fill<<<FB, 256, 0, stream>>>(ei, ew, cnt, csr);
    k_deg<<<NODE4, 256, 0, stream>>>(csr, cnt, dinv);
    k_init_h<<<IHB, 256, 0, stream>>>(x, emb, ftW, ftb, Wctp, combb, h);
    for (int L = 0; L < NLAYERS; ++L) {
        k_gemm<<<(NN + BM - 1) / BM, 256, 0, stream>>>(h, Wtp + (size_t)L * 64 * HID, dinv, xt);
        k_aggregate<<<AGB, 256, 0, stream>>>(xt, h, cnt, csr, dinv,
                                             convb + L * HID, gamma, beta, mean, var,
                                             linW, linb, out, L == NLAYERS - 1);
    }
}